// Round 16
// baseline (63.080 us; speedup 1.0000x reference)
//
#include <hip/hip_runtime.h>

#define NUM_V 100000
#define NUM_R 1000
#define ARITY 3
#define DD 128
#define DI 192   /* D + I */
#define HH 128
#define BB 4096
#define NN 64

typedef __attribute__((ext_vector_type(4))) float f32x4;
typedef __attribute__((ext_vector_type(8))) _Float16 half8;
typedef __attribute__((ext_vector_type(2))) _Float16 half2v;

// ---------------- Fused GEMM + prep, dual-tile up-front burst ----------------
// R16: completes the {in-flight depth x residency} grid. R14 (16 w/CU,
// 1-tile burst, 3 serial blocks/CU) = 57.3; R15 (8 w/CU, pipelined) = 58.0.
// This cell: 16 waves/CU AND all bursts up front -- each wave owns <=2 tiles
// (slot, slot+4096) and issues BOTH 12-load bursts (24 KB -> 96 VGPR) in the
// prologue, before the B-build and the single barrier. Per-CU in-flight at
// t=0 ~384 KB (highest of any round); ZERO memory issue during compute.
// 512 blocks x 512 thr, 2 blocks/CU resident (launch_bounds(512,4) -> VGPR
// cap 128; R15 measured 96 for the same va array). B-build 782->512 blocks.
// Prior facts honored: acc in AGPRs; loads can't sink past __syncthreads;
// nt-stores regress (R11); prep fusion worth ~8.5us (R12).
__global__ __launch_bounds__(512, 4) void gemm_fused(
    const float* __restrict__ A, const float* __restrict__ WV, const float* __restrict__ bV,
    const float* __restrict__ R, const float* __restrict__ WR, const float* __restrict__ bR,
    const float* __restrict__ P, const float* __restrict__ WP, const float* __restrict__ bP,
    _Float16* __restrict__ VWh, _Float16* __restrict__ RWh, float* __restrict__ peProd,
    int M) {
    __shared__ unsigned short bsm[24576];  // 48 KB f16 B-table, wfrag layout

    const int tid = threadIdx.x;
    const int l = tid & 63;
    const int wv = tid >> 6;  // 0..7
    const int bid = blockIdx.x;

    const int slot = bid * 8 + wv;        // 0..4095
    const bool has2 = (slot < 2154);      // tiles: slot, slot+4096 (6250 total)
    // 6250 tiles x 16 rows = 100000 = M exactly: no row clamping needed.

    // lane-invariant A base: row (l&15), k-chunk (l>>4)*8; tile t adds t*16*DI
    const float* abase = A + (size_t)(l & 15) * DI + (l >> 4) * 8;

    f32x4 va[2][6][2];  // two full tiles in registers, static indices

#define BURST(buf, t)                                                  \
    do {                                                               \
        const float* bp_ = abase + (size_t)(t) * (16 * DI);            \
        _Pragma("unroll") for (int ks = 0; ks < 6; ++ks) {             \
            va[buf][ks][0] = *(const f32x4*)(bp_ + ks * 32);           \
            va[buf][ks][1] = *(const f32x4*)(bp_ + ks * 32 + 4);       \
        }                                                              \
    } while (0)

#define COMPUTE(buf)                                                   \
    _Pragma("unroll") for (int ks = 0; ks < 6; ++ks) {                 \
        half8 ah;                                                      \
        ah[0] = (_Float16)va[buf][ks][0].x;                            \
        ah[1] = (_Float16)va[buf][ks][0].y;                            \
        ah[2] = (_Float16)va[buf][ks][0].z;                            \
        ah[3] = (_Float16)va[buf][ks][0].w;                            \
        ah[4] = (_Float16)va[buf][ks][1].x;                            \
        ah[5] = (_Float16)va[buf][ks][1].y;                            \
        ah[6] = (_Float16)va[buf][ks][1].z;                            \
        ah[7] = (_Float16)va[buf][ks][1].w;                            \
        _Pragma("unroll") for (int ct = 0; ct < 8; ++ct) {             \
            const int fb = (ks * 8 + ct) * 512;                        \
            half8 bh = *(const half8*)&bsm[fb + l * 8];                \
            acc[ct] = __builtin_amdgcn_mfma_f32_16x16x32_f16(ah, bh, acc[ct], 0, 0, 0); \
        }                                                              \
    }

#define STORE(t)                                                       \
    do {                                                               \
        const int rb_ = (t) * 16 + ((l >> 4) << 2);                    \
        _Pragma("unroll") for (int j = 0; j < 4; ++j) {                \
            _Pragma("unroll") for (int ct = 0; ct < 8; ++ct)           \
                VWh[(size_t)(rb_ + j) * HH + ct * 16 + (l & 15)] =     \
                    (_Float16)(acc[ct][j] + bcol[ct]);                 \
        }                                                              \
    } while (0)

    // ---- prologue: ALL bursts up front, pinned before the B-build
    BURST(0, slot);
    if (has2) {                 // wave-uniform branch
        BURST(1, slot + 4096);
    }
    __builtin_amdgcn_sched_barrier(0);

    // bias per col-tile
    float bcol[8];
#pragma unroll
    for (int ct = 0; ct < 8; ++ct) bcol[ct] = bV[ct * 16 + (l & 15)];

    // ---- build f16 B-table in LDS from WV (L2-hot; overlaps burst latency)
    // ushort idx = (ks*8+ct)*512 + lane*8 + j holds f16(WV[k][col]),
    // k = ks*32+(lane>>4)*8+j, col = ct*16+(lane&15)  (wfrag layout).
#pragma unroll
    for (int i = 0; i < 6; ++i) {
        const int g = i * 512 + tid;          // 0..3071 (8 ushorts each)
        const int ks = g >> 9;
        const int ct = (g >> 6) & 7;
        const int ln = g & 63;
        const int col = ct * 16 + (ln & 15);
        const int kbase = ks * 32 + ((ln >> 4) << 3);
        half8 hv;
#pragma unroll
        for (int j = 0; j < 8; ++j)
            hv[j] = (_Float16)WV[(size_t)(kbase + j) * HH + col];
        *(half8*)&bsm[(size_t)g * 8] = hv;
    }

    __syncthreads();  // the ONLY barrier: publishes B-table (drains prologue)

    // ---- tile 0
    {
        f32x4 acc[8];
#pragma unroll
        for (int ct = 0; ct < 8; ++ct) acc[ct] = (f32x4){0.f, 0.f, 0.f, 0.f};
        COMPUTE(0);
        STORE(slot);
    }

    // ---- tile 1 (slots 0..2153 only)
    if (has2) {
        f32x4 acc[8];
#pragma unroll
        for (int ct = 0; ct < 8; ++ct) acc[ct] = (f32x4){0.f, 0.f, 0.f, 0.f};
        COMPUTE(1);
        STORE(slot + 4096);
    }

#undef BURST
#undef COMPUTE
#undef STORE

    // ---- fused prep work (fills the drain-tail; no barrier needed) ----
    if (bid < 500) {
        // proj: RWh rows bid*2, bid*2+1 (500*2 = 1000 = NUM_R exactly)
        if (tid < 256) {
            const int row = bid * 2 + (tid >> 7);
            const int col = tid & 127;
            float a2 = bR[col];
            const float* Rr = R + (size_t)row * DD;
            for (int d = 0; d < DD; ++d) a2 += Rr[d] * WR[(size_t)d * HH + col];
            RWh[(size_t)row * HH + col] = (_Float16)a2;
        }
    } else if (bid == 511) {
        // pe: peProd[h] = prod_a (P[a]@WP + bP)[h]
        if (tid < HH) {
            const int h = tid;
            float prod = 1.0f;
            for (int a = 0; a < ARITY; ++a) {
                float a2 = bP[h];
                for (int d = 0; d < DD; ++d) a2 += P[a * DD + d] * WP[d * HH + h];
                prod *= a2;
            }
            peProd[h] = prod;
        }
    }
}

// ---------------- Gather - product - neighbor-sum (fp16 tables) --------------
// out[b,h] = peProd[h] * sum_n RWh[r[b,n]][h] * prod_a VWh[e[a,b,n]][h]
__global__ __launch_bounds__(256) void gather_kernel(const int* __restrict__ r,
                                                     const int* __restrict__ e,
                                                     const _Float16* __restrict__ VWh,
                                                     const _Float16* __restrict__ RWh,
                                                     const float* __restrict__ peProd,
                                                     float* __restrict__ out) {
    __shared__ int rIdx[NN];
    __shared__ int eIdx[ARITY][NN];
    __shared__ float4 partial[3][16][2];

    const int b = blockIdx.x;
    const int tid = threadIdx.x;

    if (tid < NN) {
        rIdx[tid] = r[b * NN + tid];
    } else {
        int t = tid - NN;
        eIdx[t >> 6][t & 63] = e[(size_t)(t >> 6) * BB * NN + b * NN + (t & 63)];
    }
    __syncthreads();

    const int lane = tid & 63;
    const int wv = tid >> 6;    // 0..3
    const int q = lane >> 4;    // neighbor sub-slot 0..3
    const int ho = lane & 15;   // h-octet: h = ho*8 .. +8

    float acc8[8];
#pragma unroll
    for (int k = 0; k < 8; ++k) acc8[k] = 0.f;

#pragma unroll
    for (int it = 0; it < 4; ++it) {
        int n = it * 16 + wv * 4 + q;
        half8 rw = *(const half8*)(RWh + (size_t)rIdx[n] * HH + ho * 8);
        half8 v0 = *(const half8*)(VWh + (size_t)eIdx[0][n] * HH + ho * 8);
        half8 v1 = *(const half8*)(VWh + (size_t)eIdx[1][n] * HH + ho * 8);
        half8 v2 = *(const half8*)(VWh + (size_t)eIdx[2][n] * HH + ho * 8);
        half8 p = rw * v0;
        p = p * v1;
        p = p * v2;
#pragma unroll
        for (int k = 0; k < 8; ++k) acc8[k] += (float)p[k];
    }

    // combine the 4 neighbor sub-slots (lane quarters share ho)
#pragma unroll
    for (int k = 0; k < 8; ++k) {
        acc8[k] += __shfl_xor(acc8[k], 16);
        acc8[k] += __shfl_xor(acc8[k], 32);
    }

    if (wv > 0 && lane < 16) {
        partial[wv - 1][ho][0] = make_float4(acc8[0], acc8[1], acc8[2], acc8[3]);
        partial[wv - 1][ho][1] = make_float4(acc8[4], acc8[5], acc8[6], acc8[7]);
    }
    __syncthreads();
    if (wv == 0 && lane < 16) {
        float4 s0 = make_float4(acc8[0], acc8[1], acc8[2], acc8[3]);
        float4 s1 = make_float4(acc8[4], acc8[5], acc8[6], acc8[7]);
#pragma unroll
        for (int g = 0; g < 3; ++g) {
            float4 t0 = partial[g][ho][0], t1 = partial[g][ho][1];
            s0.x += t0.x; s0.y += t0.y; s0.z += t0.z; s0.w += t0.w;
            s1.x += t1.x; s1.y += t1.y; s1.z += t1.z; s1.w += t1.w;
        }
        float4 p0 = ((const float4*)peProd)[ho * 2];
        float4 p1 = ((const float4*)peProd)[ho * 2 + 1];
        ((float4*)(out + (size_t)b * HH))[ho * 2] =
            make_float4(s0.x * p0.x, s0.y * p0.y, s0.z * p0.z, s0.w * p0.w);
        ((float4*)(out + (size_t)b * HH))[ho * 2 + 1] =
            make_float4(s1.x * p1.x, s1.y * p1.y, s1.z * p1.z, s1.w * p1.w);
    }
}

// ---------------- Launch -----------------------------------------------------
extern "C" void kernel_launch(void* const* d_in, const int* in_sizes, int n_in,
                              void* d_out, int out_size, void* d_ws, size_t ws_size,
                              hipStream_t stream) {
    const int* r = (const int*)d_in[0];
    const int* e = (const int*)d_in[1];
    const float* V = (const float*)d_in[2];
    const float* R = (const float*)d_in[3];
    const float* P = (const float*)d_in[4];
    const float* WV = (const float*)d_in[5];
    const float* bV = (const float*)d_in[6];
    const float* WR = (const float*)d_in[7];
    const float* bR = (const float*)d_in[8];
    const float* WP = (const float*)d_in[9];
    const float* bP = (const float*)d_in[10];
    float* out = (float*)d_out;

    // ws layout: VWh [NUM_V,H] fp16 | RWh [NUM_R,H] fp16 | peProd [H] f32
    _Float16* VWh = (_Float16*)d_ws;
    _Float16* RWh = VWh + (size_t)NUM_V * HH;
    float* peProd = (float*)(RWh + (size_t)NUM_R * HH);

    gemm_fused<<<512, 512, 0, stream>>>(V, WV, bV, R, WR, bR, P, WP, bP,
                                        VWh, RWh, peProd, NUM_V);
    gather_kernel<<<BB, 256, 0, stream>>>(r, e, VWh, RWh, peProd, out);
}

// Round 17
// 57.630 us; speedup vs baseline: 1.0946x; 1.0946x over previous
//
#include <hip/hip_runtime.h>

#define NUM_V 100000
#define NUM_R 1000
#define ARITY 3
#define DD 128
#define DI 192   /* D + I */
#define HH 128
#define BB 4096
#define NN 64

typedef __attribute__((ext_vector_type(4))) float f32x4;
typedef __attribute__((ext_vector_type(8))) _Float16 half8;
typedef __attribute__((ext_vector_type(2))) _Float16 half2v;

// ---------------- Fused GEMM + prep, full-tile register burst ----------------
// SESSION BEST (R14, 57.3us) -- restored after R15 (pipelined, 58.0) and R16
// (dual-burst: VGPR tell 64 showed burst-2 not held; WRITE_SIZE 43.7MB showed
// write-combining broken; 63.1) both failed to beat it.
// Each wave issues ALL 12 A-loads (12 KB -> 48 VGPRs) in one up-front burst,
// overlapped with the in-LDS B-table build; __syncthreads' vmcnt drain lands
// after both. The K-loop has ZERO memory waits. One memory round-trip per
// tile at 16 waves/CU (2 blocks/CU resident, ~3 serial block-rounds/CU).
// tile = bid*8+wv: each block reads one contiguous 96 KB A-region and each
// wave writes one contiguous 8 KB C-region (write-combining intact).
// Prior facts: acc lives in AGPRs (VGPR_Count excludes it); loads cannot
// sink past __syncthreads; nt-stores regress (R11); prep fusion ~8.5us (R12).
__global__ __launch_bounds__(512, 4) void gemm_fused(
    const float* __restrict__ A, const float* __restrict__ WV, const float* __restrict__ bV,
    const float* __restrict__ R, const float* __restrict__ WR, const float* __restrict__ bR,
    const float* __restrict__ P, const float* __restrict__ WP, const float* __restrict__ bP,
    _Float16* __restrict__ VWh, _Float16* __restrict__ RWh, float* __restrict__ peProd,
    int M) {
    __shared__ unsigned short bsm[24576];  // 48 KB f16 B-table, wfrag layout

    const int tid = threadIdx.x;
    const int l = tid & 63;
    const int wv = tid >> 6;  // 0..7
    const int bid = blockIdx.x;

    const int tile = bid * 8 + wv;    // contiguous per block: 96 KB A-region
    const int rowbase = tile * 16;
    const bool active = rowbase < M;  // wave-uniform (6250*16 = M exactly)

    // A fragment pointer: row = rowbase + (l&15), k-base (l>>4)*8 (clamped)
    const float* aptr;
    {
        int rr = rowbase + (l & 15);
        if (rr >= M) rr = M - 1;
        aptr = A + (size_t)rr * DI + (l >> 4) * 8;
    }

    // ---- FULL-TILE BURST: 12 x global_load_dwordx4 (48 VGPRs), issued
    // back-to-back at t=0, unconditional (clamped), pinned before the build.
    f32x4 va[6][2];
#pragma unroll
    for (int ks = 0; ks < 6; ++ks) {
        va[ks][0] = *(const f32x4*)(aptr + ks * 32);
        va[ks][1] = *(const f32x4*)(aptr + ks * 32 + 4);
    }
    __builtin_amdgcn_sched_barrier(0);

    // bias per col-tile
    float bcol[8];
#pragma unroll
    for (int ct = 0; ct < 8; ++ct) bcol[ct] = bV[ct * 16 + (l & 15)];

    // ---- build f16 B-table in LDS from WV (L2-hot; overlaps burst latency)
    // ushort idx = (ks*8+ct)*512 + lane*8 + j  holds f16(WV[k][col]) with
    // k = ks*32+(lane>>4)*8+j, col = ct*16+(lane&15)  (wfrag layout).
#pragma unroll
    for (int i = 0; i < 6; ++i) {
        const int g = i * 512 + tid;          // group 0..3071 (8 ushorts each)
        const int ks = g >> 9;                // 0..5
        const int ct = (g >> 6) & 7;          // 0..7
        const int ln = g & 63;                // fragment lane
        const int col = ct * 16 + (ln & 15);
        const int kbase = ks * 32 + ((ln >> 4) << 3);
        half8 hv;
#pragma unroll
        for (int j = 0; j < 8; ++j)
            hv[j] = (_Float16)WV[(size_t)(kbase + j) * HH + col];
        *(half8*)&bsm[(size_t)g * 8] = hv;
    }

    __syncthreads();  // publishes B-table; vmcnt(0) drain retires the A-burst

    if (active) {
        f32x4 acc[8];
#pragma unroll
        for (int ct = 0; ct < 8; ++ct) acc[ct] = (f32x4){0.f, 0.f, 0.f, 0.f};

        // ---- K-loop: ZERO memory waits (A in registers, B in LDS)
#pragma unroll
        for (int ks = 0; ks < 6; ++ks) {
            half8 ah;
            {
                half8 t;
                t[0] = (_Float16)va[ks][0].x;
                t[1] = (_Float16)va[ks][0].y;
                t[2] = (_Float16)va[ks][0].z;
                t[3] = (_Float16)va[ks][0].w;
                t[4] = (_Float16)va[ks][1].x;
                t[5] = (_Float16)va[ks][1].y;
                t[6] = (_Float16)va[ks][1].z;
                t[7] = (_Float16)va[ks][1].w;
                ah = t;
            }
#pragma unroll
            for (int ct = 0; ct < 8; ++ct) {
                const int fb = (ks * 8 + ct) * 512;  // ushort index of fragment
                half8 bh = *(const half8*)&bsm[fb + l * 8];
                acc[ct] = __builtin_amdgcn_mfma_f32_16x16x32_f16(ah, bh, acc[ct], 0, 0, 0);
            }
        }

        // epilogue: wave writes full 256B C-lines (col = ct*16 + (l&15))
        const int rb = rowbase + (l >> 4) * 4;
#pragma unroll
        for (int j = 0; j < 4; ++j) {
            const int row = rb + j;
            if (row < M) {
#pragma unroll
                for (int ct = 0; ct < 8; ++ct)
                    VWh[(size_t)row * HH + ct * 16 + (l & 15)] = (_Float16)(acc[ct][j] + bcol[ct]);
            }
        }
    }

    // ---- fused prep work (fills the block drain-tail; no barrier needed) ----
    if (bid < 500) {
        // proj: RWh rows bid*2, bid*2+1 (500*2 = 1000 = NUM_R exactly)
        if (tid < 256) {
            const int row = bid * 2 + (tid >> 7);
            const int col = tid & 127;
            float a2 = bR[col];
            const float* Rr = R + (size_t)row * DD;
            for (int d = 0; d < DD; ++d) a2 += Rr[d] * WR[(size_t)d * HH + col];
            RWh[(size_t)row * HH + col] = (_Float16)a2;
        }
    } else if (bid == 501) {
        // pe: peProd[h] = prod_a (P[a]@WP + bP)[h]
        if (tid < HH) {
            const int h = tid;
            float prod = 1.0f;
            for (int a = 0; a < ARITY; ++a) {
                float a2 = bP[h];
                for (int d = 0; d < DD; ++d) a2 += P[a * DD + d] * WP[d * HH + h];
                prod *= a2;
            }
            peProd[h] = prod;
        }
    }
}

// ---------------- Gather - product - neighbor-sum (fp16 tables) --------------
// out[b,h] = peProd[h] * sum_n RWh[r[b,n]][h] * prod_a VWh[e[a,b,n]][h]
__global__ __launch_bounds__(256) void gather_kernel(const int* __restrict__ r,
                                                     const int* __restrict__ e,
                                                     const _Float16* __restrict__ VWh,
                                                     const _Float16* __restrict__ RWh,
                                                     const float* __restrict__ peProd,
                                                     float* __restrict__ out) {
    __shared__ int rIdx[NN];
    __shared__ int eIdx[ARITY][NN];
    __shared__ float4 partial[3][16][2];

    const int b = blockIdx.x;
    const int tid = threadIdx.x;

    if (tid < NN) {
        rIdx[tid] = r[b * NN + tid];
    } else {
        int t = tid - NN;
        eIdx[t >> 6][t & 63] = e[(size_t)(t >> 6) * BB * NN + b * NN + (t & 63)];
    }
    __syncthreads();

    const int lane = tid & 63;
    const int wv = tid >> 6;    // 0..3
    const int q = lane >> 4;    // neighbor sub-slot 0..3
    const int ho = lane & 15;   // h-octet: h = ho*8 .. +8

    float acc8[8];
#pragma unroll
    for (int k = 0; k < 8; ++k) acc8[k] = 0.f;

#pragma unroll
    for (int it = 0; it < 4; ++it) {
        int n = it * 16 + wv * 4 + q;
        half8 rw = *(const half8*)(RWh + (size_t)rIdx[n] * HH + ho * 8);
        half8 v0 = *(const half8*)(VWh + (size_t)eIdx[0][n] * HH + ho * 8);
        half8 v1 = *(const half8*)(VWh + (size_t)eIdx[1][n] * HH + ho * 8);
        half8 v2 = *(const half8*)(VWh + (size_t)eIdx[2][n] * HH + ho * 8);
        half8 p = rw * v0;
        p = p * v1;
        p = p * v2;
#pragma unroll
        for (int k = 0; k < 8; ++k) acc8[k] += (float)p[k];
    }

    // combine the 4 neighbor sub-slots (lane quarters share ho)
#pragma unroll
    for (int k = 0; k < 8; ++k) {
        acc8[k] += __shfl_xor(acc8[k], 16);
        acc8[k] += __shfl_xor(acc8[k], 32);
    }

    if (wv > 0 && lane < 16) {
        partial[wv - 1][ho][0] = make_float4(acc8[0], acc8[1], acc8[2], acc8[3]);
        partial[wv - 1][ho][1] = make_float4(acc8[4], acc8[5], acc8[6], acc8[7]);
    }
    __syncthreads();
    if (wv == 0 && lane < 16) {
        float4 s0 = make_float4(acc8[0], acc8[1], acc8[2], acc8[3]);
        float4 s1 = make_float4(acc8[4], acc8[5], acc8[6], acc8[7]);
#pragma unroll
        for (int g = 0; g < 3; ++g) {
            float4 t0 = partial[g][ho][0], t1 = partial[g][ho][1];
            s0.x += t0.x; s0.y += t0.y; s0.z += t0.z; s0.w += t0.w;
            s1.x += t1.x; s1.y += t1.y; s1.z += t1.z; s1.w += t1.w;
        }
        float4 p0 = ((const float4*)peProd)[ho * 2];
        float4 p1 = ((const float4*)peProd)[ho * 2 + 1];
        ((float4*)(out + (size_t)b * HH))[ho * 2] =
            make_float4(s0.x * p0.x, s0.y * p0.y, s0.z * p0.z, s0.w * p0.w);
        ((float4*)(out + (size_t)b * HH))[ho * 2 + 1] =
            make_float4(s1.x * p1.x, s1.y * p1.y, s1.z * p1.z, s1.w * p1.w);
    }
}

// ---------------- Launch -----------------------------------------------------
extern "C" void kernel_launch(void* const* d_in, const int* in_sizes, int n_in,
                              void* d_out, int out_size, void* d_ws, size_t ws_size,
                              hipStream_t stream) {
    const int* r = (const int*)d_in[0];
    const int* e = (const int*)d_in[1];
    const float* V = (const float*)d_in[2];
    const float* R = (const float*)d_in[3];
    const float* P = (const float*)d_in[4];
    const float* WV = (const float*)d_in[5];
    const float* bV = (const float*)d_in[6];
    const float* WR = (const float*)d_in[7];
    const float* bR = (const float*)d_in[8];
    const float* WP = (const float*)d_in[9];
    const float* bP = (const float*)d_in[10];
    float* out = (float*)d_out;

    // ws layout: VWh [NUM_V,H] fp16 | RWh [NUM_R,H] fp16 | peProd [H] f32
    _Float16* VWh = (_Float16*)d_ws;
    _Float16* RWh = VWh + (size_t)NUM_V * HH;
    float* peProd = (float*)(RWh + (size_t)NUM_R * HH);

    const int tiles = (NUM_V + 15) / 16;            // 6250
    gemm_fused<<<(tiles + 7) / 8, 512, 0, stream>>>(V, WV, bV, R, WR, bR, P, WP, bP,
                                                    VWh, RWh, peProd, NUM_V);
    gather_kernel<<<BB, 256, 0, stream>>>(r, e, VWh, RWh, peProd, out);
}